// Round 6
// baseline (29.571 us; speedup 1.0000x reference)
//
#include <hip/hip_runtime.h>
#include <hip/hip_bf16.h>
#include <math.h>

// Problem constants: H=1024, E=48, R=32
#define Hh 1024
#define Ee 48
#define Rr 32
#define PITCH_A 1028            // emb LDS pitch (floats): 1028%32=4
#define PITCH_B 516             // kB row pitch: 516%32=4

union F4 { float4 v; float f[4]; };

// ================= kA: T[128][1024] = emb @ W1seg (+b1 on rel rows) =================
// grid 256 (rt = b&7: 16 rows; ht = b>>3: 32 h), block 512 (8 waves).
// wave w owns f-range [w*128, w*128+128); lane: h4g=lane&7 (4 h), rsub=lane>>3 (2 rows).
// W1 streamed via 16-row double-buffered register pipeline (16 loads in flight).
__global__ __launch_bounds__(512) void kA_table(const float* __restrict__ ent,
                                                const float* __restrict__ rel,
                                                const float* __restrict__ W1,
                                                const float* __restrict__ b1,
                                                float* __restrict__ T) {
    __shared__ float se[16 * PITCH_A];      // 64.3 KB; reused for partials
    const int tid = threadIdx.x;
    const int rt = blockIdx.x & 7;
    const int h0 = (blockIdx.x >> 3) * 32;
    const int row0 = rt * 16;

    const float* emb; int foff;
    if (row0 < 48)      { emb = ent + row0 * Hh;        foff = 0;      }
    else if (row0 < 80) { emb = rel + (row0 - 48) * Hh; foff = Hh;     }
    else                { emb = ent + (row0 - 80) * Hh; foff = 2 * Hh; }

    // stage 16 emb rows (64KB), f4-coalesced
    for (int q = 0; q < 8; ++q) {
        const int id4 = tid + q * 512;              // 0..4095 (16 rows x 256 f4)
        const int r = id4 >> 8, o4 = id4 & 255;
        *reinterpret_cast<float4*>(&se[r * PITCH_A + o4 * 4]) =
            *reinterpret_cast<const float4*>(&emb[r * Hh + o4 * 4]);
    }
    __syncthreads();

    const int w    = tid >> 6;
    const int lane = tid & 63;
    const int h4g  = lane & 7;
    const int rsub = lane >> 3;
    const int r0 = rsub * 2, r1 = r0 + 1;
    const int fb = w * 128;

    const float* w1p = W1 + (size_t)(foff + fb) * Hh + h0 + h4g * 4;
    const float* e0p = se + r0 * PITCH_A + fb;
    const float* e1p = se + r1 * PITCH_A + fb;

    float acc0[4] = {0.f, 0.f, 0.f, 0.f};
    float acc1[4] = {0.f, 0.f, 0.f, 0.f};

    F4 wa[16], wb[16];

#define LOAD16(BUF, G)                                                        \
    _Pragma("unroll")                                                         \
    for (int c = 0; c < 16; ++c)                                              \
        BUF[c].v = *reinterpret_cast<const float4*>(w1p + (size_t)((G) * 16 + c) * Hh);

#define COMPUTE16(BUF, G)                                                     \
    _Pragma("unroll")                                                         \
    for (int s = 0; s < 4; ++s) {                                             \
        F4 e0, e1;                                                            \
        e0.v = *reinterpret_cast<const float4*>(e0p + (G) * 16 + s * 4);      \
        e1.v = *reinterpret_cast<const float4*>(e1p + (G) * 16 + s * 4);      \
        _Pragma("unroll")                                                     \
        for (int c4 = 0; c4 < 4; ++c4) {                                      \
            _Pragma("unroll")                                                 \
            for (int hh = 0; hh < 4; ++hh) {                                  \
                acc0[hh] = fmaf(e0.f[c4], BUF[s * 4 + c4].f[hh], acc0[hh]);   \
                acc1[hh] = fmaf(e1.f[c4], BUF[s * 4 + c4].f[hh], acc1[hh]);   \
            }                                                                 \
        }                                                                     \
    }

    LOAD16(wa, 0);
    LOAD16(wb, 1); COMPUTE16(wa, 0);
    LOAD16(wa, 2); COMPUTE16(wb, 1);
    LOAD16(wb, 3); COMPUTE16(wa, 2);
    LOAD16(wa, 4); COMPUTE16(wb, 3);
    LOAD16(wb, 5); COMPUTE16(wa, 4);
    LOAD16(wa, 6); COMPUTE16(wb, 5);
    LOAD16(wb, 7); COMPUTE16(wa, 6);
    COMPUTE16(wb, 7);

#undef LOAD16
#undef COMPUTE16

    // reduce 8 wave-partials via LDS (reuse se region)
    __syncthreads();
    {
        float* part = se;                    // [8 waves][64 lanes][8]
        const int base = (w * 64 + lane) * 8;
        F4 o0, o1;
#pragma unroll
        for (int c = 0; c < 4; ++c) { o0.f[c] = acc0[c]; o1.f[c] = acc1[c]; }
        *reinterpret_cast<float4*>(&part[base])     = o0.v;
        *reinterpret_cast<float4*>(&part[base + 4]) = o1.v;
    }
    __syncthreads();
    {
        // tid -> output (r = tid>>5, h = tid&31)
        const int r = tid >> 5, h = tid & 31;
        const int src = ((r >> 1) * 8 + (h >> 2)) * 8 + (r & 1) * 4 + (h & 3);
        float s = 0.f;
#pragma unroll
        for (int ww = 0; ww < 8; ++ww) s += se[ww * 512 + src];
        const int row = row0 + r;
        if (row >= 48 && row < 80) s += b1[h0 + h];
        T[row * Hh + h0 + h] = s;
    }
}

// ================= kB: triplet logits over full h, sigmoid+mask, write out =================
// grid 192 (i = b>>2, js = (b>>1)&1, ks = b&1), block 512 (8 waves).
// LDS rows: [A(1) | R(16) | B(24) | W2] x 512-h chunk (pitch 516). 2 chunks cover h=1024.
// wave w handles h-slice w*64 within each chunk; lane: jG=lane&7 (3 j), kG=lane>>3 (2 k).
__global__ __launch_bounds__(512) void kB_triplets(const float* __restrict__ T,
                                                   const float* __restrict__ W2,
                                                   const float* __restrict__ b2,
                                                   const int* __restrict__ starts,
                                                   const int* __restrict__ maxd,
                                                   float* __restrict__ out) {
    __shared__ float se[42 * PITCH_B];      // 84.7 KB; reused for partials
    const int tid = threadIdx.x;
    const int i  = blockIdx.x >> 2;
    const int js = (blockIdx.x >> 1) & 1;
    const int ks = blockIdx.x & 1;
    const int j0 = js * 24;
    const int k0 = ks * 16;

    const int w    = tid >> 6;
    const int lane = tid & 63;
    const int jG = lane & 7;
    const int kG = lane >> 3;

    float acc[3][2];
#pragma unroll
    for (int a = 0; a < 3; ++a) { acc[a][0] = 0.f; acc[a][1] = 0.f; }

    for (int c = 0; c < 2; ++c) {
        const int hbase = c * 512;
        // stage 41 T-rows + W2 slice (f4-coalesced): 42 x 128 f4
        __syncthreads();
        for (int q = 0; q < 11; ++q) {
            const int id4 = tid + q * 512;
            if (id4 < 5376) {
                const int g = id4 >> 7, o4 = id4 & 127;
                const float* src;
                if (g == 41) src = W2 + hbase + o4 * 4;
                else {
                    int grow;
                    if (g == 0)       grow = i;                   // A row (subject)
                    else if (g < 17)  grow = 48 + k0 + (g - 1);   // R rows
                    else              grow = 80 + j0 + (g - 17);  // B rows (object)
                    src = T + grow * Hh + hbase + o4 * 4;
                }
                *reinterpret_cast<float4*>(&se[g * PITCH_B + o4 * 4]) =
                    *reinterpret_cast<const float4*>(src);
            }
        }
        __syncthreads();

        const int hw = w * 64;               // wave's 64-h slice within chunk
        const float* pa = se + hw;
        const float* pw = se + 41 * PITCH_B + hw;

#pragma unroll
        for (int s = 0; s < 16; ++s) {
            const int h4 = s * 4;
            F4 av, wv, rv[2], bv[3];
            av.v = *reinterpret_cast<const float4*>(pa + h4);
            wv.v = *reinterpret_cast<const float4*>(pw + h4);
#pragma unroll
            for (int tk = 0; tk < 2; ++tk)
                rv[tk].v = *reinterpret_cast<const float4*>(se + (1 + kG + 8 * tk) * PITCH_B + hw + h4);
#pragma unroll
            for (int tj = 0; tj < 3; ++tj)
                bv[tj].v = *reinterpret_cast<const float4*>(se + (17 + jG + 8 * tj) * PITCH_B + hw + h4);

#pragma unroll
            for (int cc = 0; cc < 4; ++cc) {
                const float a = av.f[cc], w2v = wv.f[cc];
                const float p0 = a + rv[0].f[cc];
                const float p1 = a + rv[1].f[cc];
#pragma unroll
                for (int tj = 0; tj < 3; ++tj) {
                    const float bb = bv[tj].f[cc];
                    float v0 = p0 + bb; v0 = v0 > 0.f ? v0 : 0.f;
                    acc[tj][0] = fmaf(v0, w2v, acc[tj][0]);
                    float v1 = p1 + bb; v1 = v1 > 0.f ? v1 : 0.f;
                    acc[tj][1] = fmaf(v1, w2v, acc[tj][1]);
                }
            }
        }
    }

    // cross-wave reduce (8 h-slices hold the same 384 triplets), then finalize
    __syncthreads();
    {
        float* part = se;                    // [8][384]
#pragma unroll
        for (int tj = 0; tj < 3; ++tj)
#pragma unroll
            for (int tk = 0; tk < 2; ++tk)
                part[w * 384 + (tj * 8 + jG) * 16 + tk * 8 + kG] = acc[tj][tk];
    }
    __syncthreads();
    if (tid < 384) {
        float s = b2[0];
#pragma unroll
        for (int ww = 0; ww < 8; ++ww) s += se[ww * 384 + tid];
        const int jl = tid >> 4, kl = tid & 15;
        const int j = j0 + jl, k = k0 + kl;
        const float sc = 1.f / (1.f + expf(-s));
        int di = starts[i] - starts[j]; if (di < 0) di = -di;
        const bool m = (i != j) && (di <= maxd[0]);
        out[(i * Ee + j) * Rr + k] = m ? sc : 0.f;
    }
}

// ============================ launch ============================
extern "C" void kernel_launch(void* const* d_in, const int* in_sizes, int n_in,
                              void* d_out, int out_size, void* d_ws, size_t ws_size,
                              hipStream_t stream) {
    const float* ent    = (const float*)d_in[0];
    const float* rel    = (const float*)d_in[1];
    const float* W1     = (const float*)d_in[2];
    const float* b1     = (const float*)d_in[3];
    const float* W2     = (const float*)d_in[4];
    const float* b2     = (const float*)d_in[5];
    const int*   starts = (const int*)d_in[6];
    const int*   maxd   = (const int*)d_in[7];
    float* out = (float*)d_out;

    float* T = (float*)d_ws;                 // 128 x 1024 floats = 512 KB

    kA_table<<<256, 512, 0, stream>>>(ent, rel, W1, b1, T);
    kB_triplets<<<192, 512, 0, stream>>>(T, W2, b2, starts, maxd, out);
}

// Round 7
// 29.308 us; speedup vs baseline: 1.0090x; 1.0090x over previous
//
#include <hip/hip_runtime.h>
#include <hip/hip_bf16.h>
#include <math.h>

// Problem constants: H=1024, E=48, R=32
#define Hh 1024
#define Ee 48
#define Rr 32
#define PITCH_A 1028            // emb LDS pitch (floats): 1028%32=4
#define PITCH_B 516             // kB row pitch: 516%32=4

union F4 { float4 v; float f[4]; };

// ================= kA: T[128][1024] = emb @ W1seg (+b1 on rel rows) =================
// grid 256 (rt = b&7: 16 rows; ht = b>>3: 32 h), block 512 (8 waves).
// wave w owns f-range [w*128, w*128+128); lane: h4g=lane&7 (4 h), rsub=lane>>3 (2 rows).
// W1 streamed via 16-row double-buffered register pipeline (16 loads in flight).
__global__ __launch_bounds__(512) void kA_table(const float* __restrict__ ent,
                                                const float* __restrict__ rel,
                                                const float* __restrict__ W1,
                                                const float* __restrict__ b1,
                                                float* __restrict__ T) {
    __shared__ float se[16 * PITCH_A];      // 64.3 KB; reused for partials
    const int tid = threadIdx.x;
    const int rt = blockIdx.x & 7;
    const int h0 = (blockIdx.x >> 3) * 32;
    const int row0 = rt * 16;

    const float* emb; int foff;
    if (row0 < 48)      { emb = ent + row0 * Hh;        foff = 0;      }
    else if (row0 < 80) { emb = rel + (row0 - 48) * Hh; foff = Hh;     }
    else                { emb = ent + (row0 - 80) * Hh; foff = 2 * Hh; }

    // stage 16 emb rows (64KB), f4-coalesced
    for (int q = 0; q < 8; ++q) {
        const int id4 = tid + q * 512;              // 0..4095 (16 rows x 256 f4)
        const int r = id4 >> 8, o4 = id4 & 255;
        *reinterpret_cast<float4*>(&se[r * PITCH_A + o4 * 4]) =
            *reinterpret_cast<const float4*>(&emb[r * Hh + o4 * 4]);
    }
    __syncthreads();

    const int w    = tid >> 6;
    const int lane = tid & 63;
    const int h4g  = lane & 7;
    const int rsub = lane >> 3;
    const int r0 = rsub * 2, r1 = r0 + 1;
    const int fb = w * 128;

    const float* w1p = W1 + (size_t)(foff + fb) * Hh + h0 + h4g * 4;
    const float* e0p = se + r0 * PITCH_A + fb;
    const float* e1p = se + r1 * PITCH_A + fb;

    float acc0[4] = {0.f, 0.f, 0.f, 0.f};
    float acc1[4] = {0.f, 0.f, 0.f, 0.f};

    F4 wa[16], wb[16];

#define LOAD16(BUF, G)                                                        \
    _Pragma("unroll")                                                         \
    for (int c = 0; c < 16; ++c)                                              \
        BUF[c].v = *reinterpret_cast<const float4*>(w1p + (size_t)((G) * 16 + c) * Hh);

#define COMPUTE16(BUF, G)                                                     \
    _Pragma("unroll")                                                         \
    for (int s = 0; s < 4; ++s) {                                             \
        F4 e0, e1;                                                            \
        e0.v = *reinterpret_cast<const float4*>(e0p + (G) * 16 + s * 4);      \
        e1.v = *reinterpret_cast<const float4*>(e1p + (G) * 16 + s * 4);      \
        _Pragma("unroll")                                                     \
        for (int c4 = 0; c4 < 4; ++c4) {                                      \
            _Pragma("unroll")                                                 \
            for (int hh = 0; hh < 4; ++hh) {                                  \
                acc0[hh] = fmaf(e0.f[c4], BUF[s * 4 + c4].f[hh], acc0[hh]);   \
                acc1[hh] = fmaf(e1.f[c4], BUF[s * 4 + c4].f[hh], acc1[hh]);   \
            }                                                                 \
        }                                                                     \
    }

    LOAD16(wa, 0);
    LOAD16(wb, 1); COMPUTE16(wa, 0);
    LOAD16(wa, 2); COMPUTE16(wb, 1);
    LOAD16(wb, 3); COMPUTE16(wa, 2);
    LOAD16(wa, 4); COMPUTE16(wb, 3);
    LOAD16(wb, 5); COMPUTE16(wa, 4);
    LOAD16(wa, 6); COMPUTE16(wb, 5);
    LOAD16(wb, 7); COMPUTE16(wa, 6);
    COMPUTE16(wb, 7);

#undef LOAD16
#undef COMPUTE16

    // reduce 8 wave-partials via LDS (reuse se region)
    __syncthreads();
    {
        float* part = se;                    // [8 waves][64 lanes][8]
        const int base = (w * 64 + lane) * 8;
        F4 o0, o1;
#pragma unroll
        for (int c = 0; c < 4; ++c) { o0.f[c] = acc0[c]; o1.f[c] = acc1[c]; }
        *reinterpret_cast<float4*>(&part[base])     = o0.v;
        *reinterpret_cast<float4*>(&part[base + 4]) = o1.v;
    }
    __syncthreads();
    {
        // tid -> output (r = tid>>5, h = tid&31)
        const int r = tid >> 5, h = tid & 31;
        const int src = ((r >> 1) * 8 + (h >> 2)) * 8 + (r & 1) * 4 + (h & 3);
        float s = 0.f;
#pragma unroll
        for (int ww = 0; ww < 8; ++ww) s += se[ww * 512 + src];
        const int row = row0 + r;
        if (row >= 48 && row < 80) s += b1[h0 + h];
        T[row * Hh + h0 + h] = s;
    }
}

// ================= kB: triplet logits over full h, sigmoid+mask, write out =================
// grid 192 (i = b>>2, js = (b>>1)&1, ks = b&1), block 512 (8 waves).
// LDS rows: [A(1) | R(16) | B(24) | W2] x 512-h chunk (pitch 516). 2 chunks cover h=1024.
// wave w handles h-slice w*64 within each chunk; lane: jG=lane&7 (3 j), kG=lane>>3 (2 k).
__global__ __launch_bounds__(512) void kB_triplets(const float* __restrict__ T,
                                                   const float* __restrict__ W2,
                                                   const float* __restrict__ b2,
                                                   const int* __restrict__ starts,
                                                   const int* __restrict__ maxd,
                                                   float* __restrict__ out) {
    __shared__ float se[42 * PITCH_B];      // 84.7 KB; reused for partials
    const int tid = threadIdx.x;
    const int i  = blockIdx.x >> 2;
    const int js = (blockIdx.x >> 1) & 1;
    const int ks = blockIdx.x & 1;
    const int j0 = js * 24;
    const int k0 = ks * 16;

    const int w    = tid >> 6;
    const int lane = tid & 63;
    const int jG = lane & 7;
    const int kG = lane >> 3;

    float acc[3][2];
#pragma unroll
    for (int a = 0; a < 3; ++a) { acc[a][0] = 0.f; acc[a][1] = 0.f; }

    for (int c = 0; c < 2; ++c) {
        const int hbase = c * 512;
        // stage 41 T-rows + W2 slice (f4-coalesced): 42 x 128 f4
        __syncthreads();
        for (int q = 0; q < 11; ++q) {
            const int id4 = tid + q * 512;
            if (id4 < 5376) {
                const int g = id4 >> 7, o4 = id4 & 127;
                const float* src;
                if (g == 41) src = W2 + hbase + o4 * 4;
                else {
                    int grow;
                    if (g == 0)       grow = i;                   // A row (subject)
                    else if (g < 17)  grow = 48 + k0 + (g - 1);   // R rows
                    else              grow = 80 + j0 + (g - 17);  // B rows (object)
                    src = T + grow * Hh + hbase + o4 * 4;
                }
                *reinterpret_cast<float4*>(&se[g * PITCH_B + o4 * 4]) =
                    *reinterpret_cast<const float4*>(src);
            }
        }
        __syncthreads();

        const int hw = w * 64;               // wave's 64-h slice within chunk
        const float* pa = se + hw;
        const float* pw = se + 41 * PITCH_B + hw;

#pragma unroll
        for (int s = 0; s < 16; ++s) {
            const int h4 = s * 4;
            F4 av, wv, rv[2], bv[3];
            av.v = *reinterpret_cast<const float4*>(pa + h4);
            wv.v = *reinterpret_cast<const float4*>(pw + h4);
#pragma unroll
            for (int tk = 0; tk < 2; ++tk)
                rv[tk].v = *reinterpret_cast<const float4*>(se + (1 + kG + 8 * tk) * PITCH_B + hw + h4);
#pragma unroll
            for (int tj = 0; tj < 3; ++tj)
                bv[tj].v = *reinterpret_cast<const float4*>(se + (17 + jG + 8 * tj) * PITCH_B + hw + h4);

#pragma unroll
            for (int cc = 0; cc < 4; ++cc) {
                const float a = av.f[cc], w2v = wv.f[cc];
                const float p0 = a + rv[0].f[cc];
                const float p1 = a + rv[1].f[cc];
#pragma unroll
                for (int tj = 0; tj < 3; ++tj) {
                    const float bb = bv[tj].f[cc];
                    float v0 = p0 + bb; v0 = v0 > 0.f ? v0 : 0.f;
                    acc[tj][0] = fmaf(v0, w2v, acc[tj][0]);
                    float v1 = p1 + bb; v1 = v1 > 0.f ? v1 : 0.f;
                    acc[tj][1] = fmaf(v1, w2v, acc[tj][1]);
                }
            }
        }
    }

    // cross-wave reduce (8 h-slices hold the same 384 triplets), then finalize
    __syncthreads();
    {
        float* part = se;                    // [8][384]
#pragma unroll
        for (int tj = 0; tj < 3; ++tj)
#pragma unroll
            for (int tk = 0; tk < 2; ++tk)
                part[w * 384 + (tj * 8 + jG) * 16 + tk * 8 + kG] = acc[tj][tk];
    }
    __syncthreads();
    if (tid < 384) {
        float s = b2[0];
#pragma unroll
        for (int ww = 0; ww < 8; ++ww) s += se[ww * 384 + tid];
        const int jl = tid >> 4, kl = tid & 15;
        const int j = j0 + jl, k = k0 + kl;
        const float sc = 1.f / (1.f + expf(-s));
        int di = starts[i] - starts[j]; if (di < 0) di = -di;
        const bool m = (i != j) && (di <= maxd[0]);
        out[(i * Ee + j) * Rr + k] = m ? sc : 0.f;
    }
}

// ============================ launch ============================
extern "C" void kernel_launch(void* const* d_in, const int* in_sizes, int n_in,
                              void* d_out, int out_size, void* d_ws, size_t ws_size,
                              hipStream_t stream) {
    const float* ent    = (const float*)d_in[0];
    const float* rel    = (const float*)d_in[1];
    const float* W1     = (const float*)d_in[2];
    const float* b1     = (const float*)d_in[3];
    const float* W2     = (const float*)d_in[4];
    const float* b2     = (const float*)d_in[5];
    const int*   starts = (const int*)d_in[6];
    const int*   maxd   = (const int*)d_in[7];
    float* out = (float*)d_out;

    float* T = (float*)d_ws;                 // 128 x 1024 floats = 512 KB

    kA_table<<<256, 512, 0, stream>>>(ent, rel, W1, b1, T);
    kB_triplets<<<192, 512, 0, stream>>>(T, W2, b2, starts, maxd, out);
}